// Round 1
// 253.930 us; speedup vs baseline: 1.0600x; 1.0600x over previous
//
#include <hip/hip_runtime.h>

// Length_Regulate alignment matrix, one-hot formulation.
//   repeats = (int)(durations + 0.5)        [B, T]   (durations in [1,8) => repeats in 1..8)
//   ends    = inclusive_cumsum(repeats)     starts = ends - repeats
//   out[b, t, j] = 1.0f  iff  starts[j] <= t < ends[j]
//
// Output is 32*4096*512 fp32 = 268 MB but contains only ~74K ones
// (sum of repeats per batch ~= 2300 < max_len). Strategy:
//   1) hipMemsetAsync(out, 0)  -- runtime fill measured at 6.55 TB/s on this
//      chip (rocprof: fillBufferAligned 1.07GB @ 163us), i.e. the store
//      roofline. ~41 us for 268 MB.
//   2) one fused scan+scatter kernel: 32 blocks x 512 threads, LDS scan of
//      repeats, then each thread writes its <=8 ones down its column.
//      ~74K scattered 4B stores => ~5 MB of line-amplified traffic, ~5 us.
// This deletes the 16384-block streaming writer (which carried LDS staging,
// 2 barriers and a divergent binary search on every 16KB tile) and the
// 64 KB workspace round-trip entirely.

#define T_TEXT 512

__global__ __launch_bounds__(T_TEXT) void lr_scan_scatter(
        const float* __restrict__ dur,
        float* __restrict__ out,
        int max_len) {
    __shared__ int s[T_TEXT];
    const int b = blockIdx.x;
    const int tid = threadIdx.x;

    // Same FP op sequence as reference: truncate(d + 0.5) for positive d.
    const int rep = (int)(dur[b * T_TEXT + tid] + 0.5f);
    s[tid] = rep;
    __syncthreads();

    // Hillis-Steele inclusive scan over 512 elements.
    for (int off = 1; off < T_TEXT; off <<= 1) {
        int v = s[tid];
        int add = (tid >= off) ? s[tid - off] : 0;
        __syncthreads();
        s[tid] = v + add;
        __syncthreads();
    }

    int end = s[tid];
    int start = end - rep;
    if (end > max_len) end = max_len;      // clamp (defensive; sum ~2300 < 4096)

    // Column j = tid of batch b: rows [start, end) get 1.0f.
    float* col = out + ((size_t)b * max_len) * T_TEXT + tid;
    for (int t = start; t < end; ++t) {
        col[(size_t)t * T_TEXT] = 1.0f;    // <=8 stores/thread, stride 2KB
    }
}

extern "C" void kernel_launch(void* const* d_in, const int* in_sizes, int n_in,
                              void* d_out, int out_size, void* d_ws, size_t ws_size,
                              hipStream_t stream) {
    const float* dur = (const float*)d_in[0];
    float* out = (float*)d_out;

    const int BT = in_sizes[0];           // B * T_TEXT (elements) = 16384
    const int B = BT / T_TEXT;            // 32
    const int max_len = out_size / BT;    // 4096

    // Bulk zero at the measured fill roofline (6.5+ TB/s). Stream-ordered,
    // graph-capturable (harness reset uses the same mechanism).
    hipMemsetAsync(d_out, 0, (size_t)out_size * sizeof(float), stream);

    // Scatter the ~74K ones.
    lr_scan_scatter<<<B, T_TEXT, 0, stream>>>(dur, out, max_len);
}